// Round 7
// baseline (156.852 us; speedup 1.0000x reference)
//
#include <hip/hip_runtime.h>
#include <math.h>

// z = (64,64,64,64) fp32 -> 262144 vectors of dim 64; codebook = 1024 x 64 fp32.
constexpr int DIM  = 64;
constexpr int KCB  = 1024;
constexpr int NVEC = 262144;
constexpr long long NELEM = 16777216LL;
constexpr int WAVES   = 8;               // 512 threads/block
constexpr int TILES   = 8;               // 128 rows/wave -> halves LDS scan traffic
constexpr int ROWS_PB = WAVES * TILES * 16;          // 1024 rows/block
constexpr int GRID    = NVEC / ROWS_PB;  // 256 blocks = 1 per CU

typedef short bf16x8 __attribute__((ext_vector_type(8)));  // 8 bf16 = 4 VGPRs
typedef float f32x4  __attribute__((ext_vector_type(4)));
typedef float fvec4  __attribute__((ext_vector_type(4)));  // for nontemporal ld/st

// fp32 -> bf16 round-to-nearest-even, result in low 16 bits
__device__ __forceinline__ unsigned f2bfu(float f) {
    union { float f; unsigned u; } v; v.f = f;
    return (v.u + 0x7fffu + ((v.u >> 16) & 1u)) >> 16;
}

// (u & 0xFFFFFC00) | cv in ONE VALU op.
__device__ __forceinline__ float pack_dc(unsigned u, unsigned cv, unsigned msk) {
    unsigned r;
    asm("v_bfi_b32 %0, %1, %2, %3" : "=v"(r) : "v"(msk), "v"(u), "v"(cv));
    return __uint_as_float(r);
}

// Single dispatch, one block per CU, ONE barrier. Whole codebook in LDS as
// bf16(-2*cb), XOR-swizzled (16-B unit `part` of codeword `col` at slot
// col*8+((part+col)&7) => ds_read_b128 fragments ~2-way, free).
// 8 waves x 128 rows: per-CU LDS scan traffic = 8 x 128 KB = 1 MB (half of
// round-5's 2 MB). Each 4x ds_read_b128 bundle feeds 32 MFMA. Pack/min of
// tile t-2 is interleaved with tile t's MFMAs (separate pipes, m114) so the
// VALU hides under MFMA execution instead of serializing after it.
// Loss from the tracked packed min: ||z-e||^2 = ||z||^2 + (||e||^2 - 2<e,z>).
__global__ __launch_bounds__(512, 2) void vq_fused(
        const float* __restrict__ z,
        const float* __restrict__ cb,
        float* __restrict__ out,
        float* __restrict__ ws) {

    __shared__ unsigned sB[KCB * 32];        // 128 KB swizzled bf16(-2*cb)
    __shared__ float    s_esq[KCB];          // 4 KB ||e_k||^2
    __shared__ int      s_idx[WAVES * 128];  // 4 KB per-wave argmin exchange
    __shared__ float    s_red[WAVES];        // block loss partials

    const int tid  = threadIdx.x;
    const int lane = tid & 63;
    const int wave = tid >> 6;
    const int quad = lane >> 4;
    const int lrow = lane & 15;
    const int r0   = blockIdx.x * ROWS_PB + wave * (TILES * 16);

    // ---- A fragments FIRST (cold per-block HBM read; latency hides under
    //      cb staging below). A[m=lrow][k=quad*8+j], bf16(z); exact fp32
    //      ||z||^2 partials. Nontemporal: z is read-once streaming. ----
    bf16x8 a0[TILES], a1[TILES];
    float zsq = 0.f;
    #pragma unroll
    for (int t = 0; t < TILES; ++t) {
        const fvec4* zr = (const fvec4*)(z + (size_t)(r0 + t * 16 + lrow) * DIM + quad * 8);
        fvec4 p0 = __builtin_nontemporal_load(zr);
        fvec4 p1 = __builtin_nontemporal_load(zr + 1);
        fvec4 p2 = __builtin_nontemporal_load(zr + 8);
        fvec4 p3 = __builtin_nontemporal_load(zr + 9);
        zsq = fmaf(p0[0], p0[0], zsq); zsq = fmaf(p0[1], p0[1], zsq);
        zsq = fmaf(p0[2], p0[2], zsq); zsq = fmaf(p0[3], p0[3], zsq);
        zsq = fmaf(p1[0], p1[0], zsq); zsq = fmaf(p1[1], p1[1], zsq);
        zsq = fmaf(p1[2], p1[2], zsq); zsq = fmaf(p1[3], p1[3], zsq);
        zsq = fmaf(p2[0], p2[0], zsq); zsq = fmaf(p2[1], p2[1], zsq);
        zsq = fmaf(p2[2], p2[2], zsq); zsq = fmaf(p2[3], p2[3], zsq);
        zsq = fmaf(p3[0], p3[0], zsq); zsq = fmaf(p3[1], p3[1], zsq);
        zsq = fmaf(p3[2], p3[2], zsq); zsq = fmaf(p3[3], p3[3], zsq);
        a0[t][0] = (short)f2bfu(p0[0]); a0[t][1] = (short)f2bfu(p0[1]);
        a0[t][2] = (short)f2bfu(p0[2]); a0[t][3] = (short)f2bfu(p0[3]);
        a0[t][4] = (short)f2bfu(p1[0]); a0[t][5] = (short)f2bfu(p1[1]);
        a0[t][6] = (short)f2bfu(p1[2]); a0[t][7] = (short)f2bfu(p1[3]);
        a1[t][0] = (short)f2bfu(p2[0]); a1[t][1] = (short)f2bfu(p2[1]);
        a1[t][2] = (short)f2bfu(p2[2]); a1[t][3] = (short)f2bfu(p2[3]);
        a1[t][4] = (short)f2bfu(p3[0]); a1[t][5] = (short)f2bfu(p3[1]);
        a1[t][6] = (short)f2bfu(p3[2]); a1[t][7] = (short)f2bfu(p3[3]);
    }

    // ---- build B in LDS (swizzled) + esq from fp32 cb: 512 threads x 16
    //      chunks of 512 slots. slot s = c*512+tid; col=s>>3, jj=tid&7,
    //      part=(jj-col)&7; 8 consecutive lanes = 8 parts of one codeword. ----
    {
        const int jj = tid & 7;
        #pragma unroll
        for (int c = 0; c < 16; ++c) {
            const int col  = c * 64 + (tid >> 3);
            const int part = (jj - col) & 7;
            const float* src = cb + col * DIM + part * 8;
            float4 v0 = *(const float4*)(src);
            float4 v1 = *(const float4*)(src + 4);
            float es = v0.x * v0.x;
            es = fmaf(v0.y, v0.y, es);
            es = fmaf(v0.z, v0.z, es);
            es = fmaf(v0.w, v0.w, es);
            es = fmaf(v1.x, v1.x, es);
            es = fmaf(v1.y, v1.y, es);
            es = fmaf(v1.z, v1.z, es);
            es = fmaf(v1.w, v1.w, es);
            es += __shfl_xor(es, 1, 64);
            es += __shfl_xor(es, 2, 64);
            es += __shfl_xor(es, 4, 64);
            if (jj == 0) s_esq[col] = es;
            uint4 w;
            w.x = f2bfu(-2.f * v0.x) | (f2bfu(-2.f * v0.y) << 16);
            w.y = f2bfu(-2.f * v0.z) | (f2bfu(-2.f * v0.w) << 16);
            w.z = f2bfu(-2.f * v1.x) | (f2bfu(-2.f * v1.y) << 16);
            w.w = f2bfu(-2.f * v1.z) | (f2bfu(-2.f * v1.w) << 16);
            *(uint4*)((char*)sB + (size_t)(c * 512 + tid) * 16) = w;
        }
    }

    __syncthreads();   // the ONLY staging barrier; waves free-run after this

    const int pos0 = ((quad + lrow) & 7) * 4;       // b0: part=quad   (K 0..31)
    const int pos1 = ((quad + 4 + lrow) & 7) * 4;   // b1: part=quad+4 (K 32..63)
    const int base = lrow * 32;
    const unsigned msk = 0xFFFFFC00u;

    float best[TILES][4];
    #pragma unroll
    for (int t = 0; t < TILES; ++t)
        #pragma unroll
        for (int i = 0; i < 4; ++i) best[t][i] = INFINITY;

    // ---- single scan: 32 iters x (4 ds_read_b128 -> 32 MFMA, lag-2 consume)
    for (int ks = 0; ks < 64; ks += 2) {
        const unsigned* bpA = sB + ks * 512 + base;
        const unsigned* bpB = bpA + 512;
        bf16x8 b0A = *(const bf16x8*)(bpA + pos0);
        bf16x8 b1A = *(const bf16x8*)(bpA + pos1);
        bf16x8 b0B = *(const bf16x8*)(bpB + pos0);
        bf16x8 b1B = *(const bf16x8*)(bpB + pos1);
        const float esA = s_esq[ks * 16 + lrow];
        const float esB = s_esq[ks * 16 + 16 + lrow];
        const unsigned cvA = (unsigned)(ks * 16 + lrow);
        const unsigned cvB = cvA + 16u;
        const f32x4 esvA = { esA, esA, esA, esA };   // shared C operand
        const f32x4 esvB = { esB, esB, esB, esB };
        f32x4 accA[TILES], accB[TILES];

#define CONSUME(tt) do {                                                     \
        _Pragma("unroll")                                                    \
        for (int i = 0; i < 4; ++i) {                                        \
            float pkA = pack_dc(__float_as_uint(accA[tt][i]), cvA, msk);     \
            float pkB = pack_dc(__float_as_uint(accB[tt][i]), cvB, msk);     \
            best[tt][i] = fminf(best[tt][i], fminf(pkA, pkB));               \
        } } while (0)

        __builtin_amdgcn_s_setprio(1);
        #pragma unroll
        for (int t = 0; t < TILES; ++t) {
            f32x4 xA = __builtin_amdgcn_mfma_f32_16x16x32_bf16(a0[t], b0A, esvA, 0, 0, 0);
            accA[t]  = __builtin_amdgcn_mfma_f32_16x16x32_bf16(a1[t], b1A, xA, 0, 0, 0);
            f32x4 xB = __builtin_amdgcn_mfma_f32_16x16x32_bf16(a0[t], b0B, esvB, 0, 0, 0);
            accB[t]  = __builtin_amdgcn_mfma_f32_16x16x32_bf16(a1[t], b1B, xB, 0, 0, 0);
            if (t >= 2) CONSUME(t - 2);     // VALU overlaps tile t's MFMAs
        }
        __builtin_amdgcn_s_setprio(0);
        CONSUME(TILES - 2);
        CONSUME(TILES - 1);
#undef CONSUME
    }

    // ---- min across the 16-lane col group (butterfly) ----
    #pragma unroll
    for (int t = 0; t < TILES; ++t)
        #pragma unroll
        for (int i = 0; i < 4; ++i) {
            float bs = best[t][i];
            bs = fminf(bs, __shfl_xor(bs, 1, 64));
            bs = fminf(bs, __shfl_xor(bs, 2, 64));
            bs = fminf(bs, __shfl_xor(bs, 4, 64));
            bs = fminf(bs, __shfl_xor(bs, 8, 64));
            best[t][i] = bs;
        }

    // lane lrow owns pairs p = 2*lrow, 2*lrow+1 (p = t*4+i); row of p =
    // (p>>2)*16 + quad*4 + (p&3). Static selection only (rule #20).
    float mypk0 = best[0][0], mypk1 = best[0][1];
    #pragma unroll
    for (int t = 0; t < TILES; ++t)
        #pragma unroll
        for (int i = 0; i < 4; ++i) {
            const int p = t * 4 + i;
            if ((p >> 1) == lrow) {
                if (p & 1) mypk1 = best[t][i]; else mypk0 = best[t][i];
            }
        }

    const unsigned ub0 = __float_as_uint(mypk0);
    const unsigned ub1 = __float_as_uint(mypk1);
    {
        const int p0r = 2 * lrow, p1r = 2 * lrow + 1;
        s_idx[wave * 128 + (p0r >> 2) * 16 + quad * 4 + (p0r & 3)] = (int)(ub0 & 0x3FFu);
        s_idx[wave * 128 + (p1r >> 2) * 16 + quad * 4 + (p1r & 3)] = (int)(ub1 & 0x3FFu);
    }
    // loss: ||z||^2 partial + (||e||^2 - 2<e,z>) of the two owned rows
    float lsum = zsq + __uint_as_float(ub0 & msk) + __uint_as_float(ub1 & msk);

    // wave-local LDS exchange: same wave writes then reads; fence lgkm only.
    asm volatile("s_waitcnt lgkmcnt(0)" ::: "memory");

    // ---- epilogue: gather exact fp32 codebook rows, coalesced nt store ----
    const fvec4* cb4 = (const fvec4*)cb;
    fvec4* out4 = (fvec4*)out;
    #pragma unroll 4
    for (int g = 0; g < 32; ++g) {
        const int rr = g * 4 + quad;                 // 4 rows / iteration
        const int idx = s_idx[wave * 128 + rr];      // broadcast read
        fvec4 e = cb4[idx * 16 + lrow];
        __builtin_nontemporal_store(e, &out4[(size_t)(r0 + rr) * 16 + lrow]);
    }

    // ---- loss: wave reduce -> LDS -> one atomic per block ----
    #pragma unroll
    for (int off = 32; off > 0; off >>= 1)
        lsum += __shfl_down(lsum, off, 64);
    if (lane == 0) s_red[wave] = lsum;
    __syncthreads();
    if (tid == 0) {
        float bs = 0.f;
        #pragma unroll
        for (int w = 0; w < WAVES; ++w) bs += s_red[w];
        atomicAdd(ws, bs);
        // make the loss add globally visible before the arrival counter
        asm volatile("s_waitcnt vmcnt(0)" ::: "memory");
        unsigned old = atomicAdd((unsigned*)ws + 1, 1u);
        if (old == (unsigned)(GRID - 1)) {
            float s = atomicAdd(ws, 0.0f);   // coherent read of final sum
            out[NELEM] = 1.25f * s * (1.0f / (float)NELEM);
        }
    }
}

extern "C" void kernel_launch(void* const* d_in, const int* in_sizes, int n_in,
                              void* d_out, int out_size, void* d_ws, size_t ws_size,
                              hipStream_t stream) {
    const float* z  = (const float*)d_in[0];
    const float* cb = (const float*)d_in[1];
    float* out = (float*)d_out;
    float* ws  = (float*)d_ws;   // [0]=loss accum, [1]=block counter

    hipMemsetAsync(ws, 0, 8, stream);
    vq_fused<<<GRID, 512, 0, stream>>>(z, cb, out, ws);
}